// Round 1
// baseline (1106.621 us; speedup 1.0000x reference)
//
#include <hip/hip_runtime.h>
#include <hip/hip_bf16.h>
#include <cstdint>
#include <math.h>

#define TOKENS 4096
#define DMODEL 4096
#define DFF    16384

typedef __attribute__((ext_vector_type(4))) int i32x4;
typedef __attribute__((address_space(1))) unsigned int glb_u32;
typedef __attribute__((address_space(3))) unsigned int lds_u32;

// ---------------- pack: int32 -> int8 (values already in [-127,127]) ----------------
__global__ void pack_i8_kernel(const int* __restrict__ src, unsigned* __restrict__ dst, long n4) {
    long i = (long)blockIdx.x * blockDim.x + threadIdx.x;
    const long stride = (long)gridDim.x * blockDim.x;
    for (; i < n4; i += stride) {
        const int4 v = ((const int4*)src)[i];
        unsigned p = (unsigned(v.x) & 255u) | ((unsigned(v.y) & 255u) << 8) |
                     ((unsigned(v.z) & 255u) << 16) | ((unsigned(v.w) & 255u) << 24);
        dst[i] = p;
    }
}

__global__ void zero_u32_kernel(unsigned* __restrict__ p, int n) {
    int i = blockIdx.x * blockDim.x + threadIdx.x;
    if (i < n) p[i] = 0u;
}

// ---------------- int8 GEMM, C[row][col] = sum_k A[row][k]*B[col][k] ----------------
// 128x128 tile, BK=64, 4 waves (2x2), each wave 64x64 via 4x4 frags of 16x16x64 i8 MFMA.
// LDS tiles [128][64] int8 with chunk-XOR swizzle: chunk' = chunk ^ ((row>>1)&3)
// -> conflict-free ds_read_b128 AND linear-dest global_load_lds (source pre-swizzled).
template <int EPI>
__global__ __launch_bounds__(256)
void gemm_i8_kernel(const int8_t* __restrict__ A,
                    const int8_t* __restrict__ B,
                    const int Nout, const int K,
                    const float* __restrict__ scaleA,   // EPI1: in_scale[row]
                    const float* __restrict__ scaleB,   // w1_scale / w2_scale [col]
                    const float* __restrict__ bias,     // b1 / b2 [col]
                    unsigned* __restrict__ rowmax,      // EPI1: atomic out; EPI2: in
                    __hip_bfloat16* __restrict__ aout,  // EPI1: activations out
                    float* __restrict__ out)            // EPI2: final out
{
    __shared__ int8_t As[128 * 64];
    __shared__ int8_t Bs[128 * 64];
    const int tid  = threadIdx.x;
    const int lane = tid & 63;
    const int w    = tid >> 6;
    const int wm   = w >> 1, wn = w & 1;
    const int l15  = lane & 15, l4 = lane >> 4;
    const int row0 = blockIdx.y * 128;
    const int col0 = blockIdx.x * 128;

    i32x4 acc[4][4] = {};

    for (int k0 = 0; k0 < K; k0 += 64) {
        // stage A and B tiles: per wave 2 issues x 1KB each per tile
#pragma unroll
        for (int i = 0; i < 2; ++i) {
            const int s = w * 128 + i * 64 + lane;     // 16B slot id [0,512)
            const int r = s >> 2;                      // local row [0,128)
            const int chunk = (s & 3) ^ ((r >> 1) & 3);// pre-swizzled global chunk
            const int8_t* gpA = A + (size_t)(row0 + r) * K + k0 + chunk * 16;
            const int8_t* gpB = B + (size_t)(col0 + r) * K + k0 + chunk * 16;
            int8_t* lpA = As + (w * 128 + i * 64) * 16; // wave-uniform LDS base
            int8_t* lpB = Bs + (w * 128 + i * 64) * 16;
            __builtin_amdgcn_global_load_lds((glb_u32*)gpA, (lds_u32*)lpA, 16, 0, 0);
            __builtin_amdgcn_global_load_lds((glb_u32*)gpB, (lds_u32*)lpB, 16, 0, 0);
        }
        __syncthreads();

        i32x4 af[4], bf[4];
#pragma unroll
        for (int m = 0; m < 4; ++m) {
            const int r = wm * 64 + m * 16 + l15;
            const int c = l4 ^ ((r >> 1) & 3);
            af[m] = *(const i32x4*)(As + r * 64 + c * 16);
        }
#pragma unroll
        for (int n = 0; n < 4; ++n) {
            const int r = wn * 64 + n * 16 + l15;
            const int c = l4 ^ ((r >> 1) & 3);
            bf[n] = *(const i32x4*)(Bs + r * 64 + c * 16);
        }
#pragma unroll
        for (int m = 0; m < 4; ++m)
#pragma unroll
            for (int n = 0; n < 4; ++n)
                acc[m][n] = __builtin_amdgcn_mfma_i32_16x16x64_i8(af[m], bf[n], acc[m][n], 0, 0, 0);
        __syncthreads();
    }

    // C/D frag mapping (gfx950, dtype-independent): col = lane&15, row = (lane>>4)*4 + reg
    if (EPI == 1) {
#pragma unroll
        for (int m = 0; m < 4; ++m) {
#pragma unroll
            for (int reg = 0; reg < 4; ++reg) {
                const int grow = row0 + wm * 64 + m * 16 + l4 * 4 + reg;
                const float sa = scaleA[grow];
                float vmax = 0.0f;
#pragma unroll
                for (int n = 0; n < 4; ++n) {
                    const int gcol = col0 + wn * 64 + n * 16 + l15;
                    const float y = (float)acc[m][n][reg] * sa * scaleB[gcol] + bias[gcol];
                    const float g = 0.5f * y * (1.0f + erff(y * 0.70710678118654752f));
                    aout[(size_t)grow * DFF + gcol] = __float2bfloat16(g);
                    vmax = fmaxf(vmax, fabsf(g));
                }
#pragma unroll
                for (int off = 1; off < 16; off <<= 1)
                    vmax = fmaxf(vmax, __shfl_xor(vmax, off));
                if (l15 == 0) atomicMax(&rowmax[grow], __float_as_uint(vmax));
            }
        }
    } else {
#pragma unroll
        for (int m = 0; m < 4; ++m) {
#pragma unroll
            for (int reg = 0; reg < 4; ++reg) {
                const int grow = row0 + wm * 64 + m * 16 + l4 * 4 + reg;
                const float s2 = fmaxf(__uint_as_float(rowmax[grow]) * (1.0f / 127.0f), 1e-8f);
#pragma unroll
                for (int n = 0; n < 4; ++n) {
                    const int gcol = col0 + wn * 64 + n * 16 + l15;
                    out[(size_t)grow * Nout + gcol] =
                        (float)acc[m][n][reg] * s2 * scaleB[gcol] + bias[gcol];
                }
            }
        }
    }
}

// ---------------- dynamic requant: q2 = clip(rint(a / s2), -128, 127) ----------------
__global__ void quant_kernel(const unsigned short* __restrict__ a,  // bf16 bits
                             const unsigned* __restrict__ rowmax,
                             int8_t* __restrict__ q2)
{
    const size_t nvec = (size_t)TOKENS * DFF / 8;
    size_t i = (size_t)blockIdx.x * blockDim.x + threadIdx.x;
    const size_t stride = (size_t)gridDim.x * blockDim.x;
    for (; i < nvec; i += stride) {
        const size_t e0 = i * 8;
        const int n = (int)(e0 >> 14);  // / DFF
        const float s2 = fmaxf(__uint_as_float(rowmax[n]) * (1.0f / 127.0f), 1e-8f);
        const float inv = 1.0f / s2;
        const uint4 v = *(const uint4*)(a + e0);
        const unsigned words[4] = {v.x, v.y, v.z, v.w};
        int qi[8];
#pragma unroll
        for (int j = 0; j < 4; ++j) {
            const float f0 = __uint_as_float((words[j] & 0xffffu) << 16);
            const float f1 = __uint_as_float(words[j] & 0xffff0000u);
            qi[2 * j]     = (int)fminf(fmaxf(rintf(f0 * inv), -128.0f), 127.0f);
            qi[2 * j + 1] = (int)fminf(fmaxf(rintf(f1 * inv), -128.0f), 127.0f);
        }
        const unsigned p0 = (unsigned(qi[0]) & 255u) | ((unsigned(qi[1]) & 255u) << 8) |
                            ((unsigned(qi[2]) & 255u) << 16) | ((unsigned(qi[3]) & 255u) << 24);
        const unsigned p1 = (unsigned(qi[4]) & 255u) | ((unsigned(qi[5]) & 255u) << 8) |
                            ((unsigned(qi[6]) & 255u) << 16) | ((unsigned(qi[7]) & 255u) << 24);
        ((uint2*)q2)[i] = make_uint2(p0, p1);
    }
}

extern "C" void kernel_launch(void* const* d_in, const int* in_sizes, int n_in,
                              void* d_out, int out_size, void* d_ws, size_t ws_size,
                              hipStream_t stream) {
    const int*   q_in     = (const int*)d_in[0];
    const float* in_scale = (const float*)d_in[1];
    const int*   w1_q     = (const int*)d_in[2];
    const float* w1_scale = (const float*)d_in[3];
    const float* b1       = (const float*)d_in[4];
    const int*   w2_q     = (const int*)d_in[5];
    const float* w2_scale = (const float*)d_in[6];
    const float* b2       = (const float*)d_in[7];
    float* out = (float*)d_out;

    // workspace layout (total 336 MiB + 16 KiB)
    char* ws = (char*)d_ws;
    int8_t* A1 = (int8_t*)(ws);                                  //  16 MiB  q_in int8
    int8_t* W1 = (int8_t*)(ws + (size_t)16  * 1048576);          //  64 MiB
    int8_t* W2 = (int8_t*)(ws + (size_t)80  * 1048576);          //  64 MiB
    int8_t* Q2 = (int8_t*)(ws + (size_t)144 * 1048576);          //  64 MiB
    unsigned short* ABUF = (unsigned short*)(ws + (size_t)208 * 1048576);  // 128 MiB bf16 acts
    unsigned* ROWMAX = (unsigned*)(ws + (size_t)336 * 1048576);  //  16 KiB

    zero_u32_kernel<<<dim3(16), dim3(256), 0, stream>>>(ROWMAX, TOKENS);
    pack_i8_kernel<<<dim3(1024), dim3(256), 0, stream>>>(q_in, (unsigned*)A1, (long)TOKENS * DMODEL / 4);
    pack_i8_kernel<<<dim3(4096), dim3(256), 0, stream>>>(w1_q, (unsigned*)W1, (long)DFF * DMODEL / 4);
    pack_i8_kernel<<<dim3(4096), dim3(256), 0, stream>>>(w2_q, (unsigned*)W2, (long)DMODEL * DFF / 4);

    gemm_i8_kernel<1><<<dim3(DFF / 128, TOKENS / 128), dim3(256), 0, stream>>>(
        A1, W1, DFF, DMODEL, in_scale, w1_scale, b1, ROWMAX,
        (__hip_bfloat16*)ABUF, nullptr);

    quant_kernel<<<dim3(4096), dim3(256), 0, stream>>>(ABUF, ROWMAX, Q2);

    gemm_i8_kernel<2><<<dim3(DMODEL / 128, TOKENS / 128), dim3(256), 0, stream>>>(
        Q2, W2, DMODEL, DFF, nullptr, w2_scale, b2, ROWMAX,
        nullptr, out);
}

// Round 2
// 851.768 us; speedup vs baseline: 1.2992x; 1.2992x over previous
//
#include <hip/hip_runtime.h>
#include <hip/hip_bf16.h>
#include <cstdint>
#include <math.h>

#define TOKENS 4096
#define DMODEL 4096
#define DFF    16384

typedef __attribute__((ext_vector_type(4))) int i32x4;
typedef __attribute__((address_space(1))) unsigned int glb_u32;
typedef __attribute__((address_space(3))) unsigned int lds_u32;

// ---------------- pack: int32 -> int8 (values already in [-127,127]) ----------------
__global__ void pack_i8_kernel(const int* __restrict__ src, unsigned* __restrict__ dst, long n4) {
    long i = (long)blockIdx.x * blockDim.x + threadIdx.x;
    const long stride = (long)gridDim.x * blockDim.x;
    for (; i < n4; i += stride) {
        const int4 v = ((const int4*)src)[i];
        unsigned p = (unsigned(v.x) & 255u) | ((unsigned(v.y) & 255u) << 8) |
                     ((unsigned(v.z) & 255u) << 16) | ((unsigned(v.w) & 255u) << 24);
        dst[i] = p;
    }
}

__global__ void zero_u32_kernel(unsigned* __restrict__ p, int n) {
    int i = blockIdx.x * blockDim.x + threadIdx.x;
    if (i < n) p[i] = 0u;
}

// ---------------- int8 GEMM, C[row][col] = sum_k A[row][k]*B[col][k] ----------------
// 256x256 tile, BK=128, 8 waves (2M x 4N), each wave 128x64 out via 8x4 frags of
// 16x16x64 i8 MFMA. 4 phases per K-tile:
//   p0: ds_read kk0 frags (12 b128) -> lgkmcnt(0) -> 16 MFMA (m0-3,kk0) -> bar
//   p1: ds_read kk1 frags (12 b128) -> 16 MFMA (m4-7,kk0) -> lgkmcnt(0) -> bar
//   p2: stage A(t+2) (4 gload_lds) -> 16 MFMA (m0-3,kk1) -> bar
//   p3: stage B(t+2) (4 gload_lds) -> 16 MFMA (m4-7,kk1) -> vmcnt(8) -> bar
// Race audit: all reads of buf t%2 complete (lgkmcnt-drained) before p1's barrier;
// stage issues for tile t+2 (same buf) only occur in p2/p3 after that barrier.
// vmcnt(8) at tile end leaves exactly tile t+2's 8 loads/wave in flight -> tile t+1
// resident after the barrier. LDS swizzle: chunk ^= (row&7) (16B granule) ->
// 2 lanes/bank on ds_read_b128 (free); gload_lds dest linear, source pre-swizzled.
template <int EPI>
__global__ __launch_bounds__(512)
void gemm_i8_kernel(const int8_t* __restrict__ A,
                    const int8_t* __restrict__ B,
                    const int Nout, const int K,
                    const float* __restrict__ scaleA,   // EPI1: in_scale[row]
                    const float* __restrict__ scaleB,   // w1_scale / w2_scale [col]
                    const float* __restrict__ bias,     // b1 / b2 [col]
                    unsigned* __restrict__ rowmax,      // EPI1: atomic out; EPI2: in
                    __hip_bfloat16* __restrict__ aout,  // EPI1: activations out
                    float* __restrict__ out)            // EPI2: final out
{
    __shared__ int8_t As[2][256 * 128];
    __shared__ int8_t Bs[2][256 * 128];

    const int tid  = threadIdx.x;
    const int lane = tid & 63;
    const int w    = tid >> 6;          // 0..7
    const int wm   = w >> 2;            // 0..1  (M half: 128 rows)
    const int wn   = w & 3;             // 0..3  (N quarter: 64 cols)
    const int l15  = lane & 15, l4 = lane >> 4;

    // XCD-chunked bijective block swizzle (nwg % 8 == 0 for both GEMMs here)
    const int gx  = gridDim.x;
    const int nwg = gx * gridDim.y;
    int wg = blockIdx.y * gx + blockIdx.x;
    wg = (wg & 7) * (nwg >> 3) + (wg >> 3);
    const int col0 = (wg % gx) * 256;
    const int row0 = (wg / gx) * 256;

    const int nt = K >> 7;

    // staging geometry: per operand 4 units of 8KB (64 rows x 128B); per wave 1KB/unit
    const int rw = (w << 3) + (lane >> 3);          // row within unit's 64-row span? no:
    // unit u covers rows u*64..u*64+63; wave w writes rows u*64 + w*8 .. +8
    const int g16 = ((lane & 7) ^ (lane >> 3)) << 4; // pre-swizzled source chunk byte

    // ds_read addressing (swizzled): row r, chunk c = (kk*4+l4) ^ (r&7); r&7 == l15&7
    const int rbA = (((wm << 7) + l15) << 7);        // byte base; + m*2048
    const int rbB = (((wn << 6) + l15) << 7);        // byte base; + n*2048
    const int c0  = (l4 ^ (l15 & 7)) << 4;           // kk0 chunk byte; kk1 = c0 ^ 64

    i32x4 acc[8][4] = {};

#define STAGE_OP(P, p0q, LDSBUF, t)                                                   \
    {                                                                                 \
        const int k0_ = (t) << 7;                                                     \
        const int8_t* src_ = (P) + (size_t)((p0q) + (w << 3) + (lane >> 3)) * K +     \
                             k0_ + g16;                                               \
        int8_t* dst_ = &LDSBUF[(t) & 1][w << 10];                                     \
        _Pragma("unroll")                                                             \
        for (int u_ = 0; u_ < 4; ++u_)                                                \
            __builtin_amdgcn_global_load_lds((glb_u32*)(src_ + (size_t)(u_ * 64) * K),\
                                             (lds_u32*)(dst_ + u_ * 8192), 16, 0, 0); \
    }

    // prologue: tiles 0 and 1
    STAGE_OP(A, row0, As, 0);
    STAGE_OP(B, col0, Bs, 0);
    STAGE_OP(A, row0, As, 1);
    STAGE_OP(B, col0, Bs, 1);
    asm volatile("s_waitcnt vmcnt(8)" ::: "memory");
    __builtin_amdgcn_s_barrier();

    for (int t = 0; t < nt; ++t) {
        const int buf = t & 1;
        const int tn = (t + 2 < nt) ? (t + 2) : (nt - 1);
        i32x4 a0[8], b0[4], a1[8], b1[4];

        // ---- phase 0: read kk0 frags, MFMA (m0-3, kk0) ----
#pragma unroll
        for (int m = 0; m < 8; ++m)
            a0[m] = *(const i32x4*)(&As[buf][rbA + m * 2048 + c0]);
#pragma unroll
        for (int n = 0; n < 4; ++n)
            b0[n] = *(const i32x4*)(&Bs[buf][rbB + n * 2048 + c0]);
        asm volatile("s_waitcnt lgkmcnt(0)" ::: "memory");
        __builtin_amdgcn_sched_barrier(0);
        __builtin_amdgcn_s_setprio(1);
#pragma unroll
        for (int m = 0; m < 4; ++m)
#pragma unroll
            for (int n = 0; n < 4; ++n)
                acc[m][n] = __builtin_amdgcn_mfma_i32_16x16x64_i8(a0[m], b0[n], acc[m][n], 0, 0, 0);
        __builtin_amdgcn_s_setprio(0);
        __builtin_amdgcn_s_barrier();

        // ---- phase 1: read kk1 frags, MFMA (m4-7, kk0), drain reads ----
#pragma unroll
        for (int m = 0; m < 8; ++m)
            a1[m] = *(const i32x4*)(&As[buf][rbA + m * 2048 + (c0 ^ 64)]);
#pragma unroll
        for (int n = 0; n < 4; ++n)
            b1[n] = *(const i32x4*)(&Bs[buf][rbB + n * 2048 + (c0 ^ 64)]);
        __builtin_amdgcn_s_setprio(1);
#pragma unroll
        for (int m = 4; m < 8; ++m)
#pragma unroll
            for (int n = 0; n < 4; ++n)
                acc[m][n] = __builtin_amdgcn_mfma_i32_16x16x64_i8(a0[m], b0[n], acc[m][n], 0, 0, 0);
        __builtin_amdgcn_s_setprio(0);
        asm volatile("s_waitcnt lgkmcnt(0)" ::: "memory");
        __builtin_amdgcn_sched_barrier(0);
        __builtin_amdgcn_s_barrier();

        // ---- phase 2: stage A(t+2), MFMA (m0-3, kk1) ----
        STAGE_OP(A, row0, As, tn);
        __builtin_amdgcn_s_setprio(1);
#pragma unroll
        for (int m = 0; m < 4; ++m)
#pragma unroll
            for (int n = 0; n < 4; ++n)
                acc[m][n] = __builtin_amdgcn_mfma_i32_16x16x64_i8(a1[m], b1[n], acc[m][n], 0, 0, 0);
        __builtin_amdgcn_s_setprio(0);
        __builtin_amdgcn_s_barrier();

        // ---- phase 3: stage B(t+2), MFMA (m4-7, kk1), counted vmcnt ----
        STAGE_OP(B, col0, Bs, tn);
        __builtin_amdgcn_s_setprio(1);
#pragma unroll
        for (int m = 4; m < 8; ++m)
#pragma unroll
            for (int n = 0; n < 4; ++n)
                acc[m][n] = __builtin_amdgcn_mfma_i32_16x16x64_i8(a1[m], b1[n], acc[m][n], 0, 0, 0);
        __builtin_amdgcn_s_setprio(0);
        asm volatile("s_waitcnt vmcnt(8)" ::: "memory");
        __builtin_amdgcn_s_barrier();
    }
#undef STAGE_OP

    // C/D frag mapping (gfx950, dtype-independent): col = lane&15, row = (lane>>4)*4 + reg
    if (EPI == 1) {
#pragma unroll
        for (int m = 0; m < 8; ++m) {
#pragma unroll
            for (int reg = 0; reg < 4; ++reg) {
                const int grow = row0 + (wm << 7) + m * 16 + l4 * 4 + reg;
                const float sa = scaleA[grow];
                float vmax = 0.0f;
#pragma unroll
                for (int n = 0; n < 4; ++n) {
                    const int gcol = col0 + (wn << 6) + n * 16 + l15;
                    const float y = (float)acc[m][n][reg] * sa * scaleB[gcol] + bias[gcol];
                    const float gl = 0.5f * y * (1.0f + erff(y * 0.70710678118654752f));
                    aout[(size_t)grow * DFF + gcol] = __float2bfloat16(gl);
                    vmax = fmaxf(vmax, fabsf(gl));
                }
#pragma unroll
                for (int off = 1; off < 16; off <<= 1)
                    vmax = fmaxf(vmax, __shfl_xor(vmax, off));
                if (l15 == 0) atomicMax(&rowmax[grow], __float_as_uint(vmax));
            }
        }
    } else {
#pragma unroll
        for (int m = 0; m < 8; ++m) {
#pragma unroll
            for (int reg = 0; reg < 4; ++reg) {
                const int grow = row0 + (wm << 7) + m * 16 + l4 * 4 + reg;
                const float s2 = fmaxf(__uint_as_float(rowmax[grow]) * (1.0f / 127.0f), 1e-8f);
#pragma unroll
                for (int n = 0; n < 4; ++n) {
                    const int gcol = col0 + (wn << 6) + n * 16 + l15;
                    out[(size_t)grow * Nout + gcol] =
                        (float)acc[m][n][reg] * s2 * scaleB[gcol] + bias[gcol];
                }
            }
        }
    }
}

// ---------------- dynamic requant: q2 = clip(rint(a / s2), -128, 127) ----------------
__global__ void quant_kernel(const unsigned short* __restrict__ a,  // bf16 bits
                             const unsigned* __restrict__ rowmax,
                             int8_t* __restrict__ q2)
{
    const size_t nvec = (size_t)TOKENS * DFF / 8;
    size_t i = (size_t)blockIdx.x * blockDim.x + threadIdx.x;
    const size_t stride = (size_t)gridDim.x * blockDim.x;
    for (; i < nvec; i += stride) {
        const size_t e0 = i * 8;
        const int n = (int)(e0 >> 14);  // / DFF
        const float s2 = fmaxf(__uint_as_float(rowmax[n]) * (1.0f / 127.0f), 1e-8f);
        const float inv = 1.0f / s2;
        const uint4 v = *(const uint4*)(a + e0);
        const unsigned words[4] = {v.x, v.y, v.z, v.w};
        int qi[8];
#pragma unroll
        for (int j = 0; j < 4; ++j) {
            const float f0 = __uint_as_float((words[j] & 0xffffu) << 16);
            const float f1 = __uint_as_float(words[j] & 0xffff0000u);
            qi[2 * j]     = (int)fminf(fmaxf(rintf(f0 * inv), -128.0f), 127.0f);
            qi[2 * j + 1] = (int)fminf(fmaxf(rintf(f1 * inv), -128.0f), 127.0f);
        }
        const unsigned p0 = (unsigned(qi[0]) & 255u) | ((unsigned(qi[1]) & 255u) << 8) |
                            ((unsigned(qi[2]) & 255u) << 16) | ((unsigned(qi[3]) & 255u) << 24);
        const unsigned p1 = (unsigned(qi[4]) & 255u) | ((unsigned(qi[5]) & 255u) << 8) |
                            ((unsigned(qi[6]) & 255u) << 16) | ((unsigned(qi[7]) & 255u) << 24);
        ((uint2*)q2)[i] = make_uint2(p0, p1);
    }
}

extern "C" void kernel_launch(void* const* d_in, const int* in_sizes, int n_in,
                              void* d_out, int out_size, void* d_ws, size_t ws_size,
                              hipStream_t stream) {
    const int*   q_in     = (const int*)d_in[0];
    const float* in_scale = (const float*)d_in[1];
    const int*   w1_q     = (const int*)d_in[2];
    const float* w1_scale = (const float*)d_in[3];
    const float* b1       = (const float*)d_in[4];
    const int*   w2_q     = (const int*)d_in[5];
    const float* w2_scale = (const float*)d_in[6];
    const float* b2       = (const float*)d_in[7];
    float* out = (float*)d_out;

    // workspace layout (total 336 MiB + 16 KiB)
    char* ws = (char*)d_ws;
    int8_t* A1 = (int8_t*)(ws);                                  //  16 MiB  q_in int8
    int8_t* W1 = (int8_t*)(ws + (size_t)16  * 1048576);          //  64 MiB
    int8_t* W2 = (int8_t*)(ws + (size_t)80  * 1048576);          //  64 MiB
    int8_t* Q2 = (int8_t*)(ws + (size_t)144 * 1048576);          //  64 MiB
    unsigned short* ABUF = (unsigned short*)(ws + (size_t)208 * 1048576);  // 128 MiB bf16 acts
    unsigned* ROWMAX = (unsigned*)(ws + (size_t)336 * 1048576);  //  16 KiB

    zero_u32_kernel<<<dim3(16), dim3(256), 0, stream>>>(ROWMAX, TOKENS);
    pack_i8_kernel<<<dim3(1024), dim3(256), 0, stream>>>(q_in, (unsigned*)A1, (long)TOKENS * DMODEL / 4);
    pack_i8_kernel<<<dim3(4096), dim3(256), 0, stream>>>(w1_q, (unsigned*)W1, (long)DFF * DMODEL / 4);
    pack_i8_kernel<<<dim3(4096), dim3(256), 0, stream>>>(w2_q, (unsigned*)W2, (long)DMODEL * DFF / 4);

    gemm_i8_kernel<1><<<dim3(DFF / 256, TOKENS / 256), dim3(512), 0, stream>>>(
        A1, W1, DFF, DMODEL, in_scale, w1_scale, b1, ROWMAX,
        (__hip_bfloat16*)ABUF, nullptr);

    quant_kernel<<<dim3(4096), dim3(256), 0, stream>>>(ABUF, ROWMAX, Q2);

    gemm_i8_kernel<2><<<dim3(DMODEL / 256, TOKENS / 256), dim3(512), 0, stream>>>(
        Q2, W2, DMODEL, DFF, nullptr, w2_scale, b2, ROWMAX,
        nullptr, out);
}